// Round 11
// baseline (111.108 us; speedup 1.0000x reference)
//
#include <hip/hip_runtime.h>
#include <math.h>

// Problem constants (fixed by setup_inputs)
#define BATCH   32
#define NPTS    512
#define FDIM    320
#define FOBS    256
#define DK      64
#define MROWS   (BATCH * NPTS)            // 16384
#define A_ELEMS ((size_t)BATCH * NPTS * NPTS)  // 8388608

typedef __bf16  bf16x8 __attribute__((ext_vector_type(8)));
typedef float   f32x4  __attribute__((ext_vector_type(4)));
typedef ushort  u16x8  __attribute__((ext_vector_type(8)));
typedef ushort  u16x4  __attribute__((ext_vector_type(4)));

__device__ __forceinline__ ushort f2bf(float f) {   // RNE f32 -> bf16
    unsigned u = __builtin_bit_cast(unsigned, f);
    return (ushort)((u + 0x7fffu + ((u >> 16) & 1u)) >> 16);
}

__device__ __forceinline__ bf16x8 ld_bf8(const ushort* p) {
    return __builtin_bit_cast(bf16x8, *reinterpret_cast<const uint4*>(p));
}

// ---------------------------------------------------------------------------
// K0: Wt[n][k] = bf16( n<64 ? a_link[k][n] : b_link[k][n-64] )   (128 x 256)
// ---------------------------------------------------------------------------
__global__ __launch_bounds__(256) void k0_wt(const float* __restrict__ al,
                                             const float* __restrict__ bl,
                                             ushort* __restrict__ wt) {
    const int n = blockIdx.x;
    const int k = threadIdx.x;
    const float* src = (n < 64) ? al : bl;
    const int nn = n & 63;
    wt[(size_t)n * FOBS + k] = f2bf(src[(size_t)k * DK + nn]);
}

// ---------------------------------------------------------------------------
// K1 (frozen; ~1.6 us per R9 decomposition)
// ---------------------------------------------------------------------------
__global__ __launch_bounds__(256) void k1_mfma(const float* __restrict__ h,
                                               const ushort* __restrict__ wt,
                                               ushort* __restrict__ hi,
                                               ushort* __restrict__ hj) {
    const int t  = threadIdx.x;
    const int w  = t >> 6;
    const int l  = t & 63;
    const int lr = l & 15;
    const int lg = l >> 4;
    const int rb = blockIdx.x * 32 + 16 * (w & 1);
    const int cb = 64 * (w >> 1);

    const float* hrow = h + (size_t)(rb + lr) * FDIM;
    bf16x8 bfr[8];
#pragma unroll
    for (int ks = 0; ks < 8; ++ks) {
        const float* p = hrow + ks * 32 + lg * 8;
        float4 v0 = *reinterpret_cast<const float4*>(p);
        float4 v1 = *reinterpret_cast<const float4*>(p + 4);
        u16x8 u;
        u[0] = f2bf(v0.x); u[1] = f2bf(v0.y); u[2] = f2bf(v0.z); u[3] = f2bf(v0.w);
        u[4] = f2bf(v1.x); u[5] = f2bf(v1.y); u[6] = f2bf(v1.z); u[7] = f2bf(v1.w);
        bfr[ks] = __builtin_bit_cast(bf16x8, u);
    }

    f32x4 acc[4];
#pragma unroll
    for (int cf = 0; cf < 4; ++cf) acc[cf] = (f32x4){0.f, 0.f, 0.f, 0.f};

#pragma unroll
    for (int ks = 0; ks < 8; ++ks) {
#pragma unroll
        for (int cf = 0; cf < 4; ++cf) {
            bf16x8 afr = ld_bf8(&wt[(size_t)(cb + 16 * cf + lr) * FOBS + ks * 32 + lg * 8]);
            acc[cf] = __builtin_amdgcn_mfma_f32_16x16x32_bf16(afr, bfr[ks], acc[cf], 0, 0, 0);
        }
    }

    ushort* dst = (cb == 0) ? hi : hj;
    const size_t m = (size_t)(rb + lr);
#pragma unroll
    for (int cf = 0; cf < 4; ++cf) {
        u16x4 v;
#pragma unroll
        for (int r = 0; r < 4; ++r) v[r] = f2bf(acc[cf][r]);
        *reinterpret_cast<u16x4*>(&dst[m * DK + 16 * cf + lg * 4]) = v;
    }
}

// ---------------------------------------------------------------------------
// K2_LOOP4 (diagnostic): baseline k2 body executed 4x with laundered pointers
// so loads/MFMA cannot be hoisted across reps. One long dispatch -> counter
// row guaranteed visible above the 40us harness fills. Output identical to
// baseline (stores idempotent; lsum recomputed per rep, final rep stored).
// ---------------------------------------------------------------------------
__global__ __launch_bounds__(256, 4) void k2_loop4(const ushort* __restrict__ hi,
                                                   const ushort* __restrict__ hj,
                                                   float* __restrict__ Aout,
                                                   float* __restrict__ partials) {
    __shared__ float red[4];
    const int id  = blockIdx.x;
    const int sub = id >> 3;
    const int b   = (id & 7) * 4 + (sub >> 6);
    const int it  = (sub >> 3) & 7;
    const int jt  = sub & 7;

    const int t  = threadIdx.x;
    const int w  = t >> 6;
    const int l  = t & 63;
    const int lr = l & 15;
    const int lg = l >> 4;
    const int i0 = it * 64, j0 = jt * 64;

    const ushort* hib = hi + ((size_t)b * NPTS + i0) * DK;
    const ushort* hjb = hj + ((size_t)b * NPTS + j0) * DK;

    float lsum = 0.f;
#pragma unroll 1
    for (int rep = 0; rep < 4; ++rep) {
        const ushort* hib_ = hib;
        const ushort* hjb_ = hjb;
        asm volatile("" : "+v"(hib_), "+v"(hjb_));   // opaque: forces re-exec
        lsum = 0.f;

        bf16x8 afr[2];
#pragma unroll
        for (int ks = 0; ks < 2; ++ks)
            afr[ks] = ld_bf8(&hjb_[(size_t)(16 * w + lr) * DK + ks * 32 + lg * 8]);

        bf16x8 bfr[4][2];
#pragma unroll
        for (int itt = 0; itt < 4; ++itt)
#pragma unroll
            for (int ks = 0; ks < 2; ++ks)
                bfr[itt][ks] = ld_bf8(&hib_[(size_t)(16 * itt + lr) * DK + ks * 32 + lg * 8]);

        f32x4 acc[4];
#pragma unroll
        for (int itt = 0; itt < 4; ++itt) acc[itt] = (f32x4){0.f, 0.f, 0.f, 0.f};
#pragma unroll
        for (int ks = 0; ks < 2; ++ks)
#pragma unroll
            for (int itt = 0; itt < 4; ++itt)
                acc[itt] = __builtin_amdgcn_mfma_f32_16x16x32_bf16(
                    afr[ks], bfr[itt][ks], acc[itt], 0, 0, 0);

        const int colbase = j0 + 16 * w + 4 * lg;
#pragma unroll
        for (int itt = 0; itt < 4; ++itt) {
            const int row = i0 + 16 * itt + lr;
            f32x4 ov;
#pragma unroll
            for (int r = 0; r < 4; ++r) {
                float x  = acc[itt][r] * 0.125f;
                float ax = fabsf(x);
                float nl = __logf(1.0f + __expf(-ax));
                bool diag = (row == colbase + r);
                ov[r] = (diag || x > 0.f) ? 1.f : 0.f;
                if (!diag) lsum -= nl;
            }
            __builtin_nontemporal_store(ov,
                reinterpret_cast<f32x4*>(&Aout[((size_t)b * NPTS + row) * NPTS + colbase]));
        }
    }

#pragma unroll
    for (int off = 32; off > 0; off >>= 1) lsum += __shfl_down(lsum, off);
    if (l == 0) red[w] = lsum;
    __syncthreads();
    if (t == 0) {
        float s = (red[0] + red[1]) + (red[2] + red[3]);
        partials[(size_t)b * 64 + it * 8 + jt] = s;
    }
}

// ---------------------------------------------------------------------------
// K2FAT4 (diagnostic A/B): same math, fat blocks. 512 blocks = (b, it, jh);
// hi-frags loaded once per rep, jt-loop x4 amortizes loads + in-block ILP.
// x4 rep loop (laundered) for counter visibility. partialsF -> dead ws.
// ---------------------------------------------------------------------------
__global__ __launch_bounds__(256, 4) void k2fat4(const ushort* __restrict__ hi,
                                                 const ushort* __restrict__ hj,
                                                 float* __restrict__ Aout,
                                                 float* __restrict__ partialsF) {
    __shared__ float red[4];
    const int id = blockIdx.x;          // 512 blocks
    const int b  = id >> 4;
    const int it = (id >> 1) & 7;
    const int jh = id & 1;
    const int i0 = it * 64;

    const int t  = threadIdx.x;
    const int w  = t >> 6;
    const int l  = t & 63;
    const int lr = l & 15;
    const int lg = l >> 4;

    const ushort* hib  = hi + ((size_t)b * NPTS + i0) * DK;
    const ushort* hjb0 = hj + ((size_t)b * NPTS + jh * 256) * DK;

    float lsum = 0.f;
#pragma unroll 1
    for (int rep = 0; rep < 4; ++rep) {
        const ushort* hib_  = hib;
        const ushort* hjb0_ = hjb0;
        asm volatile("" : "+v"(hib_), "+v"(hjb0_));
        lsum = 0.f;

        bf16x8 bfr[4][2];
#pragma unroll
        for (int itt = 0; itt < 4; ++itt)
#pragma unroll
            for (int ks = 0; ks < 2; ++ks)
                bfr[itt][ks] = ld_bf8(&hib_[(size_t)(16 * itt + lr) * DK + ks * 32 + lg * 8]);

#pragma unroll 2
        for (int jt2 = 0; jt2 < 4; ++jt2) {
            const ushort* hjb_ = hjb0_ + (size_t)jt2 * 64 * DK;
            bf16x8 afr[2];
#pragma unroll
            for (int ks = 0; ks < 2; ++ks)
                afr[ks] = ld_bf8(&hjb_[(size_t)(16 * w + lr) * DK + ks * 32 + lg * 8]);

            f32x4 acc[4];
#pragma unroll
            for (int itt = 0; itt < 4; ++itt) acc[itt] = (f32x4){0.f, 0.f, 0.f, 0.f};
#pragma unroll
            for (int ks = 0; ks < 2; ++ks)
#pragma unroll
                for (int itt = 0; itt < 4; ++itt)
                    acc[itt] = __builtin_amdgcn_mfma_f32_16x16x32_bf16(
                        afr[ks], bfr[itt][ks], acc[itt], 0, 0, 0);

            const int j0 = jh * 256 + jt2 * 64;
            const int colbase = j0 + 16 * w + 4 * lg;
#pragma unroll
            for (int itt = 0; itt < 4; ++itt) {
                const int row = i0 + 16 * itt + lr;
                f32x4 ov;
#pragma unroll
                for (int r = 0; r < 4; ++r) {
                    float x  = acc[itt][r] * 0.125f;
                    float ax = fabsf(x);
                    float nl = __logf(1.0f + __expf(-ax));
                    bool diag = (row == colbase + r);
                    ov[r] = (diag || x > 0.f) ? 1.f : 0.f;
                    if (!diag) lsum -= nl;
                }
                __builtin_nontemporal_store(ov,
                    reinterpret_cast<f32x4*>(&Aout[((size_t)b * NPTS + row) * NPTS + colbase]));
            }
        }
    }

#pragma unroll
    for (int off = 32; off > 0; off >>= 1) lsum += __shfl_down(lsum, off);
    if (l == 0) red[w] = lsum;
    __syncthreads();
    if (t == 0) {
        float s = (red[0] + red[1]) + (red[2] + red[3]);
        partialsF[id] = s;   // dead ws store (not validated) — keeps work live
    }
}

// ---------------------------------------------------------------------------
// K3: probs[b] = sum of 64 tile partials (deterministic wave reduction)
// ---------------------------------------------------------------------------
__global__ __launch_bounds__(64) void k3_reduce(const float* __restrict__ partials,
                                                float* __restrict__ probs) {
    int b = blockIdx.x;
    float s = partials[(size_t)b * 64 + threadIdx.x];
#pragma unroll
    for (int off = 32; off > 0; off >>= 1) s += __shfl_down(s, off);
    if (threadIdx.x == 0) probs[b] = s;
}

extern "C" void kernel_launch(void* const* d_in, const int* in_sizes, int n_in,
                              void* d_out, int out_size, void* d_ws, size_t ws_size,
                              hipStream_t stream) {
    const float* h  = (const float*)d_in[0];
    const float* al = (const float*)d_in[1];
    const float* bl = (const float*)d_in[2];
    float* out = (float*)d_out;

    ushort* hi       = (ushort*)d_ws;                      // 16384*64 bf16 (2 MB)
    ushort* hj       = hi + (size_t)MROWS * DK;            // 16384*64 bf16 (2 MB)
    ushort* wt       = hj + (size_t)MROWS * DK;            // 128*256 bf16 (64 KB)
    float* partials  = (float*)(wt + 128 * FOBS);          // 32*64 f32
    float* partialsF = partials + BATCH * 64;              // 512 f32 (dead)

    k0_wt<<<128, 256, 0, stream>>>(al, bl, wt);

    k1_mfma<<<MROWS / 32, 256, 0, stream>>>(h, wt, hi, hj);

    // A/B diagnostic: fat variant first (its A_out is overwritten below).
    k2fat4<<<512, 256, 0, stream>>>(hi, hj, out, partialsF);

    k2_loop4<<<(NPTS / 64) * (NPTS / 64) * BATCH, 256, 0, stream>>>(
        hi, hj, out, partials);

    k3_reduce<<<BATCH, 64, 0, stream>>>(partials, out + A_ELEMS);
}

// Round 12
// 41.531 us; speedup vs baseline: 2.6753x; 2.6753x over previous
//
#include <hip/hip_runtime.h>
#include <math.h>

// Problem constants (fixed by setup_inputs)
#define BATCH   32
#define NPTS    512
#define FDIM    320
#define FOBS    256
#define DK      64
#define MROWS   (BATCH * NPTS)            // 16384
#define A_ELEMS ((size_t)BATCH * NPTS * NPTS)  // 8388608

typedef __bf16  bf16x8 __attribute__((ext_vector_type(8)));
typedef float   f32x4  __attribute__((ext_vector_type(4)));
typedef ushort  u16x8  __attribute__((ext_vector_type(8)));
typedef ushort  u16x4  __attribute__((ext_vector_type(4)));

__device__ __forceinline__ ushort f2bf(float f) {   // RNE f32 -> bf16
    unsigned u = __builtin_bit_cast(unsigned, f);
    return (ushort)((u + 0x7fffu + ((u >> 16) & 1u)) >> 16);
}

__device__ __forceinline__ bf16x8 ld_bf8(const ushort* p) {
    return __builtin_bit_cast(bf16x8, *reinterpret_cast<const uint4*>(p));
}

__device__ __forceinline__ bf16x8 cvt8(const float* p) {
    float4 v0 = *reinterpret_cast<const float4*>(p);
    float4 v1 = *reinterpret_cast<const float4*>(p + 4);
    u16x8 u;
    u[0] = f2bf(v0.x); u[1] = f2bf(v0.y); u[2] = f2bf(v0.z); u[3] = f2bf(v0.w);
    u[4] = f2bf(v1.x); u[5] = f2bf(v1.y); u[6] = f2bf(v1.z); u[7] = f2bf(v1.w);
    return __builtin_bit_cast(bf16x8, u);
}

// ---------------------------------------------------------------------------
// K0: Wt[n][k] = bf16( n<64 ? a_link[k][n] : b_link[k][n-64] )   (128 x 256)
// ---------------------------------------------------------------------------
__global__ __launch_bounds__(256) void k0_wt(const float* __restrict__ al,
                                             const float* __restrict__ bl,
                                             ushort* __restrict__ wt) {
    const int n = blockIdx.x;
    const int k = threadIdx.x;
    const float* src = (n < 64) ? al : bl;
    const int nn = n & 63;
    wt[(size_t)n * FOBS + k] = f2bf(src[(size_t)k * DK + nn]);
}

// ---------------------------------------------------------------------------
// K1 (re-grid for occupancy): 1024 blocks x 16 rows. The 4 waves split the
// 128 output cols (32 each: 2cf x 8ks = 16 MFMA) and SHARE the block's 16
// h-rows via L1/L2 -> 16 waves/CU (was 8). Same math/layout as before:
// store n = cbN+16cf2+4lg+r at lane-row m = rb+lr, u16x4.
// ---------------------------------------------------------------------------
__global__ __launch_bounds__(256) void k1_mfma(const float* __restrict__ h,
                                               const ushort* __restrict__ wt,
                                               ushort* __restrict__ hi,
                                               ushort* __restrict__ hj) {
    const int t  = threadIdx.x;
    const int w  = t >> 6;
    const int l  = t & 63;
    const int lr = l & 15;
    const int lg = l >> 4;
    const int rb  = blockIdx.x * 16;
    const int cbN = 32 * w;              // output col base: 0,32 -> hi; 64,96 -> hj

    const float* hrow = h + (size_t)(rb + lr) * FDIM;
    bf16x8 bfr[8];
#pragma unroll
    for (int ks = 0; ks < 8; ++ks) bfr[ks] = cvt8(hrow + ks * 32 + lg * 8);

    f32x4 acc[2];
#pragma unroll
    for (int cf = 0; cf < 2; ++cf) acc[cf] = (f32x4){0.f, 0.f, 0.f, 0.f};

#pragma unroll
    for (int ks = 0; ks < 8; ++ks) {
#pragma unroll
        for (int cf = 0; cf < 2; ++cf) {
            bf16x8 afr = ld_bf8(&wt[(size_t)(cbN + 16 * cf + lr) * FOBS + ks * 32 + lg * 8]);
            acc[cf] = __builtin_amdgcn_mfma_f32_16x16x32_bf16(afr, bfr[ks], acc[cf], 0, 0, 0);
        }
    }

    ushort* dst = (w >= 2) ? hj : hi;
    const int nb = cbN & 63;
    const size_t m = (size_t)(rb + lr);
#pragma unroll
    for (int cf = 0; cf < 2; ++cf) {
        u16x4 v;
#pragma unroll
        for (int r = 0; r < 4; ++r) v[r] = f2bf(acc[cf][r]);
        *reinterpret_cast<u16x4*>(&dst[m * DK + nb + 16 * cf + 4 * lg]) = v;
    }
}

// ---------------------------------------------------------------------------
// K2FAT (R11's k2fat4, 1 rep): 512 blocks = (b, it, jh). hi-frags loaded
// once, jt-loop x4 amortizes + gives in-block ILP. Swapped-operand MFMA,
// D[j][i] -> f32x4 NT stores. lsum over the block's 64x256 region ->
// partials[id] (16 per batch).
// ---------------------------------------------------------------------------
__global__ __launch_bounds__(256, 4) void k2fat(const ushort* __restrict__ hi,
                                                const ushort* __restrict__ hj,
                                                float* __restrict__ Aout,
                                                float* __restrict__ partials) {
    __shared__ float red[4];
    const int id = blockIdx.x;          // 512 blocks
    const int b  = id >> 4;
    const int it = (id >> 1) & 7;
    const int jh = id & 1;
    const int i0 = it * 64;

    const int t  = threadIdx.x;
    const int w  = t >> 6;
    const int l  = t & 63;
    const int lr = l & 15;
    const int lg = l >> 4;

    const ushort* hib  = hi + ((size_t)b * NPTS + i0) * DK;
    const ushort* hjb0 = hj + ((size_t)b * NPTS + jh * 256) * DK;

    float lsum = 0.f;

    bf16x8 bfr[4][2];
#pragma unroll
    for (int itt = 0; itt < 4; ++itt)
#pragma unroll
        for (int ks = 0; ks < 2; ++ks)
            bfr[itt][ks] = ld_bf8(&hib[(size_t)(16 * itt + lr) * DK + ks * 32 + lg * 8]);

#pragma unroll 2
    for (int jt2 = 0; jt2 < 4; ++jt2) {
        const ushort* hjb = hjb0 + (size_t)jt2 * 64 * DK;
        bf16x8 afr[2];
#pragma unroll
        for (int ks = 0; ks < 2; ++ks)
            afr[ks] = ld_bf8(&hjb[(size_t)(16 * w + lr) * DK + ks * 32 + lg * 8]);

        f32x4 acc[4];
#pragma unroll
        for (int itt = 0; itt < 4; ++itt) acc[itt] = (f32x4){0.f, 0.f, 0.f, 0.f};
#pragma unroll
        for (int ks = 0; ks < 2; ++ks)
#pragma unroll
            for (int itt = 0; itt < 4; ++itt)
                acc[itt] = __builtin_amdgcn_mfma_f32_16x16x32_bf16(
                    afr[ks], bfr[itt][ks], acc[itt], 0, 0, 0);

        const int j0 = jh * 256 + jt2 * 64;
        const int colbase = j0 + 16 * w + 4 * lg;
#pragma unroll
        for (int itt = 0; itt < 4; ++itt) {
            const int row = i0 + 16 * itt + lr;
            f32x4 ov;
#pragma unroll
            for (int r = 0; r < 4; ++r) {
                float x  = acc[itt][r] * 0.125f;   // / sqrt(64), tau = 1
                float ax = fabsf(x);
                float nl = __logf(1.0f + __expf(-ax));   // -log(sel), sel >= 0.5
                bool diag = (row == colbase + r);
                ov[r] = (diag || x > 0.f) ? 1.f : 0.f;
                if (!diag) lsum -= nl;
            }
            __builtin_nontemporal_store(ov,
                reinterpret_cast<f32x4*>(&Aout[((size_t)b * NPTS + row) * NPTS + colbase]));
        }
    }

    // deterministic block reduction of lsum
#pragma unroll
    for (int off = 32; off > 0; off >>= 1) lsum += __shfl_down(lsum, off);
    if (l == 0) red[w] = lsum;
    __syncthreads();
    if (t == 0) {
        float s = (red[0] + red[1]) + (red[2] + red[3]);
        partials[id] = s;
    }
}

// ---------------------------------------------------------------------------
// K3: probs[b] = sum of 16 block partials (deterministic)
// ---------------------------------------------------------------------------
__global__ __launch_bounds__(64) void k3_reduce(const float* __restrict__ partials,
                                                float* __restrict__ probs) {
    int b = blockIdx.x;
    float s = (threadIdx.x < 16) ? partials[b * 16 + threadIdx.x] : 0.f;
#pragma unroll
    for (int off = 32; off > 0; off >>= 1) s += __shfl_down(s, off);
    if (threadIdx.x == 0) probs[b] = s;
}

extern "C" void kernel_launch(void* const* d_in, const int* in_sizes, int n_in,
                              void* d_out, int out_size, void* d_ws, size_t ws_size,
                              hipStream_t stream) {
    const float* h  = (const float*)d_in[0];
    const float* al = (const float*)d_in[1];
    const float* bl = (const float*)d_in[2];
    float* out = (float*)d_out;

    ushort* hi      = (ushort*)d_ws;                      // 16384*64 bf16 (2 MB)
    ushort* hj      = hi + (size_t)MROWS * DK;            // 16384*64 bf16 (2 MB)
    ushort* wt      = hj + (size_t)MROWS * DK;            // 128*256 bf16 (64 KB)
    float* partials = (float*)(wt + 128 * FOBS);          // 512 f32

    k0_wt<<<128, 256, 0, stream>>>(al, bl, wt);

    k1_mfma<<<MROWS / 16, 256, 0, stream>>>(h, wt, hi, hj);

    k2fat<<<512, 256, 0, stream>>>(hi, hj, out, partials);

    k3_reduce<<<BATCH, 64, 0, stream>>>(partials, out + A_ELEMS);
}